// Round 22
// baseline (50.766 us; speedup 1.0000x reference)
//
#include <hip/hip_runtime.h>

typedef _Float16 half8_t __attribute__((ext_vector_type(8)));
typedef _Float16 half4_t __attribute__((ext_vector_type(4)));
typedef __attribute__((ext_vector_type(4))) float float4_t;

#define MFMA16 __builtin_amdgcn_mfma_f32_16x16x32_f16

constexpr int BB   = 4;
constexpr int LL   = 2048;
constexpr int DM   = 1024;
constexpr int DK   = 128;
constexpr int MTOT = BB * LL;     // 8192
constexpr int MC   = 8;
constexpr float INV2PI = 0.15915494309189535f;

__device__ __forceinline__ void gload16(const void* g, void* l) {
    __builtin_amdgcn_global_load_lds(
        (const __attribute__((address_space(1))) void*)g,
        (__attribute__((address_space(3))) void*)l, 16, 0, 0);
}

// ---------------------------------------------------------------------------
// K0: W [1024 k][128 n] f32 -> fragment-major W^T fp16 image.
// Per kc (64-k chunk): [cbt 8][s 8][cc 16][e 8]; n=cbt*16+cc,
// k = (s>>2)*32 + (s&3)*8 + e.  grid (16 kc, 3 arr).
// ---------------------------------------------------------------------------
__global__ __launch_bounds__(256) void k0_wsplit(
        const float* __restrict__ wq, const float* __restrict__ wk,
        const float* __restrict__ wv,
        _Float16* __restrict__ wq6, _Float16* __restrict__ wk6,
        _Float16* __restrict__ wv6) {
    int kc = blockIdx.x, a = blockIdx.y;
    const float* w = (a == 0) ? wq : (a == 1) ? wk : wv;
    _Float16* dst = (a == 0) ? wq6 : (a == 1) ? wk6 : wv6;
    __shared__ float tile[64 * 132];
    int t = threadIdx.x;
#pragma unroll
    for (int j = 0; j < 8; ++j) {
        int idx4 = t + j * 256;
        int kr = idx4 >> 5, n4 = idx4 & 31;
        *(float4_t*)(&tile[kr * 132 + n4 * 4]) =
            *(const float4_t*)(w + (size_t)(kc * 64 + kr) * DK + n4 * 4);
    }
    __syncthreads();
#pragma unroll
    for (int sw = 0; sw < 4; ++sw) {
        int ch = t + sw * 256;
        int cbt = ch >> 7, s = (ch >> 4) & 7, cc = ch & 15;
        int kb = (s >> 2) * 32 + (s & 3) * 8;
        int n = cbt * 16 + cc;
        half8_t h;
#pragma unroll
        for (int e = 0; e < 8; ++e) h[e] = (_Float16)tile[(kb + e) * 132 + n];
        *(half8_t*)(dst + (size_t)kc * 8192 + ch * 8) = h;
    }
}

// ---------------------------------------------------------------------------
// K1 v13 (R21): R9 skeleton at 8 waves/block. BM=32, BK=64, BN=128;
// grid (256,3); block 512 (8 waves, wave tile 32r x 16c). Simple 2-phase.
// LDS 41KB -> 3 blocks/CU, 24 waves/CU.
// ---------------------------------------------------------------------------
__global__ __launch_bounds__(512, 6) void k1_proj(
        const float* __restrict__ x,
        const float* __restrict__ bq, const float* __restrict__ bk,
        const float* __restrict__ bv,
        const _Float16* __restrict__ wq6, const _Float16* __restrict__ wk6,
        const _Float16* __restrict__ wv6,
        _Float16* __restrict__ qim, _Float16* __restrict__ kim,
        _Float16* __restrict__ vim) {
    int mt = blockIdx.x, grp = blockIdx.y;
    int rowbase = mt * 32;
    __shared__ __attribute__((aligned(16))) _Float16 xs[2][32 * 72];  // 4.5KB ea
    __shared__ __attribute__((aligned(16))) _Float16 wsm[2][8192];    // 16KB ea

    int t = threadIdx.x, lane = t & 63, wid = t >> 6;   // wid 0..7
    int cc = lane & 15, g = lane >> 4;
    const _Float16* W6 = (grp == 0) ? wq6 : (grp == 1) ? wk6 : wv6;

    float4_t acc[2];
#pragma unroll
    for (int rf = 0; rf < 2; ++rf) acc[rf] = (float4_t){0.f, 0.f, 0.f, 0.f};

    bool xact = (t < 256);
    int xr = (t & 255) >> 3, xc8 = t & 7;
    const float* xsrc = x + (size_t)(rowbase + xr) * DM + xc8 * 8;
    int xoff = xr * 72 + xc8 * 8;

    auto stageW = [&](int kc, int buf) {
        const _Float16* Wp = W6 + (size_t)kc * 8192;
#pragma unroll
        for (int i = 0; i < 2; ++i)
            gload16(Wp + (size_t)(i * 512 + t) * 8,
                    (char*)wsm[buf] + i * 8192 + wid * 1024);
    };
    auto cvt8 = [&](float4_t f0, float4_t f1) {
        half8_t h;
#pragma unroll
        for (int e = 0; e < 4; ++e) { h[e] = (_Float16)f0[e]; h[e + 4] = (_Float16)f1[e]; }
        return h;
    };

    {
        stageW(0, 0);
        if (xact) {
            float4_t f0 = *(const float4_t*)(xsrc);
            float4_t f1 = *(const float4_t*)(xsrc + 4);
            *(half8_t*)(xs[0] + xoff) = cvt8(f0, f1);
        }
    }
    __syncthreads();

#pragma unroll 1
    for (int kc = 0; kc < 16; ++kc) {
        int cb = kc & 1, nb = cb ^ 1;
        bool more = (kc < 15);
        float4_t f0, f1;
        if (more) {
            if (xact) {
                f0 = *(const float4_t*)(xsrc + (size_t)(kc + 1) * 64);
                f1 = *(const float4_t*)(xsrc + (size_t)(kc + 1) * 64 + 4);
            }
            stageW(kc + 1, nb);
        }
        half8_t a_[2][2], b_[2];
#pragma unroll
        for (int rf = 0; rf < 2; ++rf)
#pragma unroll
            for (int ks = 0; ks < 2; ++ks)
                a_[rf][ks] = *(const half8_t*)(xs[cb] + (rf * 16 + cc) * 72 + ks * 32 + g * 8);
#pragma unroll
        for (int ks = 0; ks < 2; ++ks)
            b_[ks] = *(const half8_t*)(wsm[cb] + wid * 1024 + (ks * 4 + g) * 128 + cc * 8);
#pragma unroll
        for (int rf = 0; rf < 2; ++rf) {
            acc[rf] = MFMA16(a_[rf][0], b_[0], acc[rf], 0, 0, 0);
            acc[rf] = MFMA16(a_[rf][1], b_[1], acc[rf], 0, 0, 0);
        }
        if (more && xact) *(half8_t*)(xs[nb] + xoff) = cvt8(f0, f1);
        __syncthreads();
    }

    const float* bias = (grp == 0) ? bq : (grp == 1) ? bk : bv;
    int c = wid * 16 + cc;
    float bv_ = bias[c];
#pragma unroll
    for (int rf = 0; rf < 2; ++rf)
#pragma unroll
        for (int i = 0; i < 4; ++i) {
            int r = rowbase + rf * 16 + g * 4 + i;
            float v = acc[rf][i] + bv_;
            if (grp == 0) {
                size_t o = (size_t)(r >> 4) * 2048 + (c >> 5) * 512 +
                           ((c >> 3) & 3) * 128 + (r & 15) * 8 + (c & 7);
                qim[o] = (_Float16)v;
            } else if (grp == 1) {
                size_t o = (size_t)(r >> 5) * 4096 + ((r >> 4) & 1) * 2048 +
                           (c >> 5) * 512 + ((c >> 3) & 3) * 128 +
                           (r & 15) * 8 + (c & 7);
                kim[o] = (_Float16)v;
            } else {
                size_t o = (size_t)(r >> 5) * 4096 + (c >> 4) * 512 +
                           ((r >> 3) & 3) * 128 + (c & 15) * 8 + (r & 7);
                vim[o] = (_Float16)v;
            }
        }
}

// ---------------------------------------------------------------------------
// K2 v12: occupancy probe. KVBLK=32, MC=8 -> grid (8,32,4) = 1024 blocks =
// 4 blocks/CU, 16 waves/CU (2x v10). LDS 36KB. Per-CU DS/MFMA totals
// unchanged vs v10 (16 MFMA + 17 b128 + 2 b64 per wave-step, 8 steps).
// Swapped QK^T, half4 P-writes, fp16 partials.
// ---------------------------------------------------------------------------
__global__ __launch_bounds__(256) void k2_attn(
        const _Float16* __restrict__ qim, const _Float16* __restrict__ kim,
        const _Float16* __restrict__ vim, _Float16* __restrict__ part) {
    int mc = blockIdx.x, qt = blockIdx.y, b = blockIdx.z;
    int t = threadIdx.x, lane = t & 63, wid = t >> 6;
    int cc = lane & 15, g = lane >> 4;

    __shared__ __attribute__((aligned(16))) _Float16 kb[2][4096];   // 8KB ea
    __shared__ __attribute__((aligned(16))) _Float16 vb[2][4096];   // 8KB ea
    __shared__ __attribute__((aligned(16))) _Float16 ps[4][512];    // 4KB

    int qrow = b * LL + qt * 64 + wid * 16;
    const _Float16* qb_ = qim + (size_t)(qrow >> 4) * 2048;
    half8_t qf[4];
#pragma unroll
    for (int s = 0; s < 4; ++s)
        qf[s] = *(const half8_t*)(qb_ + s * 512 + g * 128 + cc * 8);

    float4_t o[8];
#pragma unroll
    for (int cf = 0; cf < 8; ++cf) o[cf] = (float4_t){0.f, 0.f, 0.f, 0.f};

    int tbase = b * 64 + mc * 8;    // 32-row tile base; 8 tiles per block

    auto stageKV = [&](int mi, int buf) {
        const _Float16* ks = kim + (size_t)(tbase + mi) * 4096;
        const _Float16* vs = vim + (size_t)(tbase + mi) * 4096;
#pragma unroll
        for (int i = 0; i < 2; ++i) {
            gload16(ks + i * 2048 + t * 8, (char*)kb[buf] + i * 4096 + wid * 1024);
            gload16(vs + i * 2048 + t * 8, (char*)vb[buf] + i * 4096 + wid * 1024);
        }
    };

    stageKV(0, 0);
    __syncthreads();

#pragma unroll 1
    for (int mi = 0; mi < 8; ++mi) {
        int cb = mi & 1, nb = cb ^ 1;
        if (mi < 7) stageKV(mi + 1, nb);
        // ---- S^T = K Q^T (swapped): lane holds q=cc, m = cf*16 + g*4 + i
        float4_t sa[2];
#pragma unroll
        for (int cf = 0; cf < 2; ++cf) sa[cf] = (float4_t){0.f, 0.f, 0.f, 0.f};
#pragma unroll
        for (int cf = 0; cf < 2; ++cf)
#pragma unroll
            for (int s = 0; s < 4; ++s) {
                half8_t kf = *(const half8_t*)(kb[cb] + cf * 2048 + s * 512 +
                                               g * 128 + cc * 8);
                sa[cf] = MFMA16(kf, qf[s], sa[cf], 0, 0, 0);
            }
        // ---- P = cos(S) -> [m>>3][q][m&7]; i=0..3 contiguous -> one b64
#pragma unroll
        for (int cf = 0; cf < 2; ++cf) {
            half4_t h4;
#pragma unroll
            for (int i = 0; i < 4; ++i) {
                float rv = sa[cf][i] * INV2PI;
                rv = rv - floorf(rv);
                float cv;
                asm volatile("v_cos_f32 %0, %1" : "=v"(cv) : "v"(rv));
                h4[i] = (_Float16)cv;
            }
            int base = (cf * 2 + (g >> 1)) * 128 + cc * 8 + (g & 1) * 4;
            *(half4_t*)(&ps[wid][base]) = h4;
        }
        // ---- out += P @ V  (k=32: one pa, 8 V-frags)
        half8_t pa = *(const half8_t*)(&ps[wid][g * 128 + cc * 8]);
#pragma unroll
        for (int cf = 0; cf < 8; ++cf) {
            half8_t vbf = *(const half8_t*)(vb[cb] + cf * 512 + g * 128 + cc * 8);
            o[cf] = MFMA16(pa, vbf, o[cf], 0, 0, 0);
        }
        __syncthreads();
    }
    // ---- store fp16 partials: layout [MC][B][L][DK]
    _Float16* pp = part + ((size_t)(mc * BB + b) * LL + qt * 64 + wid * 16) * DK;
#pragma unroll
    for (int cf = 0; cf < 8; ++cf)
#pragma unroll
        for (int i = 0; i < 4; ++i)
            pp[(g * 4 + i) * DK + cf * 16 + cc] = (_Float16)o[cf][i];
}

// ---------------------------------------------------------------------------
// K3: out = sum of MC fp16 partials (fp32 accumulate, fp32 out)
// ---------------------------------------------------------------------------
__global__ __launch_bounds__(256) void k3_reduce(const _Float16* __restrict__ part,
                                                 float4_t* __restrict__ out) {
    constexpr int NT8 = MTOT * DK / 8;   // 131072 8-elem units per chunk
    int idx = blockIdx.x * 256 + threadIdx.x;
    const half8_t* p = (const half8_t*)part;
    float s[8];
#pragma unroll
    for (int e = 0; e < 8; ++e) s[e] = 0.f;
#pragma unroll
    for (int c = 0; c < MC; ++c) {
        half8_t v = p[idx + (size_t)c * NT8];
#pragma unroll
        for (int e = 0; e < 8; ++e) s[e] += (float)v[e];
    }
    float4_t o0 = {s[0], s[1], s[2], s[3]};
    float4_t o1 = {s[4], s[5], s[6], s[7]};
    out[idx * 2]     = o0;
    out[idx * 2 + 1] = o1;
}

// ---------------------------------------------------------------------------
extern "C" void kernel_launch(void* const* d_in, const int* in_sizes, int n_in,
                              void* d_out, int out_size, void* d_ws, size_t ws_size,
                              hipStream_t stream) {
    const float* x  = (const float*)d_in[0];
    const float* Wq = (const float*)d_in[1];
    const float* bq = (const float*)d_in[2];
    const float* Wk = (const float*)d_in[3];
    const float* bk = (const float*)d_in[4];
    const float* Wv = (const float*)d_in[5];
    const float* bv = (const float*)d_in[6];

    char* ws = (char*)d_ws;
    size_t off = 0;
    auto alloc = [&](size_t bytes) -> char* {
        char* p = ws + off;
        off += (bytes + 255) & ~(size_t)255;
        return p;
    };
    _Float16* wq6 = (_Float16*)alloc((size_t)DK * DM * 2);
    _Float16* wk6 = (_Float16*)alloc((size_t)DK * DM * 2);
    _Float16* wv6 = (_Float16*)alloc((size_t)DK * DM * 2);
    _Float16* qim = (_Float16*)alloc((size_t)MTOT * DK * 2);
    _Float16* kim = (_Float16*)alloc((size_t)MTOT * DK * 2);
    _Float16* vim = (_Float16*)alloc((size_t)MTOT * DK * 2);
    _Float16* part = (_Float16*)alloc((size_t)MC * MTOT * DK * 2);

    k0_wsplit<<<dim3(16, 3), 256, 0, stream>>>(Wq, Wk, Wv, wq6, wk6, wv6);
    k1_proj<<<dim3(MTOT / 32, 3), 512, 0, stream>>>(x, bq, bk, bv,
                                                    wq6, wk6, wv6, qim, kim, vim);
    k2_attn<<<dim3(MC, LL / 64, BB), 256, 0, stream>>>(qim, kim, vim, part);
    k3_reduce<<<(MTOT * DK / 8) / 256, 256, 0, stream>>>(part, (float4_t*)d_out);
}

// Round 23
// 46.461 us; speedup vs baseline: 1.0927x; 1.0927x over previous
//
#include <hip/hip_runtime.h>

typedef _Float16 half8_t __attribute__((ext_vector_type(8)));
typedef _Float16 half4_t __attribute__((ext_vector_type(4)));
typedef __attribute__((ext_vector_type(4))) float float4_t;

#define MFMA16 __builtin_amdgcn_mfma_f32_16x16x32_f16

constexpr int BB   = 4;
constexpr int LL   = 2048;
constexpr int DM   = 1024;
constexpr int DK   = 128;
constexpr int MTOT = BB * LL;     // 8192
constexpr int MC   = 4;
constexpr float INV2PI = 0.15915494309189535f;

__device__ __forceinline__ void gload16(const void* g, void* l) {
    __builtin_amdgcn_global_load_lds(
        (const __attribute__((address_space(1))) void*)g,
        (__attribute__((address_space(3))) void*)l, 16, 0, 0);
}

// ---------------------------------------------------------------------------
// K0: W [1024 k][128 n] f32 -> fragment-major W^T fp16 image.
// Per kc (64-k chunk): [cbt 8][s 8][cc 16][e 8]; n=cbt*16+cc,
// k = (s>>2)*32 + (s&3)*8 + e.  grid (16 kc, 3 arr).
// ---------------------------------------------------------------------------
__global__ __launch_bounds__(256) void k0_wsplit(
        const float* __restrict__ wq, const float* __restrict__ wk,
        const float* __restrict__ wv,
        _Float16* __restrict__ wq6, _Float16* __restrict__ wk6,
        _Float16* __restrict__ wv6) {
    int kc = blockIdx.x, a = blockIdx.y;
    const float* w = (a == 0) ? wq : (a == 1) ? wk : wv;
    _Float16* dst = (a == 0) ? wq6 : (a == 1) ? wk6 : wv6;
    __shared__ float tile[64 * 132];
    int t = threadIdx.x;
#pragma unroll
    for (int j = 0; j < 8; ++j) {
        int idx4 = t + j * 256;
        int kr = idx4 >> 5, n4 = idx4 & 31;
        *(float4_t*)(&tile[kr * 132 + n4 * 4]) =
            *(const float4_t*)(w + (size_t)(kc * 64 + kr) * DK + n4 * 4);
    }
    __syncthreads();
#pragma unroll
    for (int sw = 0; sw < 4; ++sw) {
        int ch = t + sw * 256;
        int cbt = ch >> 7, s = (ch >> 4) & 7, cc = ch & 15;
        int kb = (s >> 2) * 32 + (s & 3) * 8;
        int n = cbt * 16 + cc;
        half8_t h;
#pragma unroll
        for (int e = 0; e < 8; ++e) h[e] = (_Float16)tile[(kb + e) * 132 + n];
        *(half8_t*)(dst + (size_t)kc * 8192 + ch * 8) = h;
    }
}

// ---------------------------------------------------------------------------
// K1 v13 (R21-proven): R9 skeleton at 8 waves/block. BM=32, BK=64, BN=128;
// grid (256,3); block 512 (8 waves, wave tile 32r x 16c). Simple 2-phase:
// stage(k+1) -> compute(k) -> one __syncthreads. LDS 41KB -> 3 blocks/CU.
// ---------------------------------------------------------------------------
__global__ __launch_bounds__(512, 6) void k1_proj(
        const float* __restrict__ x,
        const float* __restrict__ bq, const float* __restrict__ bk,
        const float* __restrict__ bv,
        const _Float16* __restrict__ wq6, const _Float16* __restrict__ wk6,
        const _Float16* __restrict__ wv6,
        _Float16* __restrict__ qim, _Float16* __restrict__ kim,
        _Float16* __restrict__ vim) {
    int mt = blockIdx.x, grp = blockIdx.y;
    int rowbase = mt * 32;
    __shared__ __attribute__((aligned(16))) _Float16 xs[2][32 * 72];  // 4.5KB ea
    __shared__ __attribute__((aligned(16))) _Float16 wsm[2][8192];    // 16KB ea

    int t = threadIdx.x, lane = t & 63, wid = t >> 6;   // wid 0..7
    int cc = lane & 15, g = lane >> 4;
    const _Float16* W6 = (grp == 0) ? wq6 : (grp == 1) ? wk6 : wv6;

    float4_t acc[2];
#pragma unroll
    for (int rf = 0; rf < 2; ++rf) acc[rf] = (float4_t){0.f, 0.f, 0.f, 0.f};

    bool xact = (t < 256);
    int xr = (t & 255) >> 3, xc8 = t & 7;
    const float* xsrc = x + (size_t)(rowbase + xr) * DM + xc8 * 8;
    int xoff = xr * 72 + xc8 * 8;

    auto stageW = [&](int kc, int buf) {
        const _Float16* Wp = W6 + (size_t)kc * 8192;
#pragma unroll
        for (int i = 0; i < 2; ++i)
            gload16(Wp + (size_t)(i * 512 + t) * 8,
                    (char*)wsm[buf] + i * 8192 + wid * 1024);
    };
    auto cvt8 = [&](float4_t f0, float4_t f1) {
        half8_t h;
#pragma unroll
        for (int e = 0; e < 4; ++e) { h[e] = (_Float16)f0[e]; h[e + 4] = (_Float16)f1[e]; }
        return h;
    };

    {
        stageW(0, 0);
        if (xact) {
            float4_t f0 = *(const float4_t*)(xsrc);
            float4_t f1 = *(const float4_t*)(xsrc + 4);
            *(half8_t*)(xs[0] + xoff) = cvt8(f0, f1);
        }
    }
    __syncthreads();

#pragma unroll 1
    for (int kc = 0; kc < 16; ++kc) {
        int cb = kc & 1, nb = cb ^ 1;
        bool more = (kc < 15);
        float4_t f0, f1;
        if (more) {
            if (xact) {
                f0 = *(const float4_t*)(xsrc + (size_t)(kc + 1) * 64);
                f1 = *(const float4_t*)(xsrc + (size_t)(kc + 1) * 64 + 4);
            }
            stageW(kc + 1, nb);
        }
        half8_t a_[2][2], b_[2];
#pragma unroll
        for (int rf = 0; rf < 2; ++rf)
#pragma unroll
            for (int ks = 0; ks < 2; ++ks)
                a_[rf][ks] = *(const half8_t*)(xs[cb] + (rf * 16 + cc) * 72 + ks * 32 + g * 8);
#pragma unroll
        for (int ks = 0; ks < 2; ++ks)
            b_[ks] = *(const half8_t*)(wsm[cb] + wid * 1024 + (ks * 4 + g) * 128 + cc * 8);
#pragma unroll
        for (int rf = 0; rf < 2; ++rf) {
            acc[rf] = MFMA16(a_[rf][0], b_[0], acc[rf], 0, 0, 0);
            acc[rf] = MFMA16(a_[rf][1], b_[1], acc[rf], 0, 0, 0);
        }
        if (more && xact) *(half8_t*)(xs[nb] + xoff) = cvt8(f0, f1);
        __syncthreads();
    }

    const float* bias = (grp == 0) ? bq : (grp == 1) ? bk : bv;
    int c = wid * 16 + cc;
    float bv_ = bias[c];
#pragma unroll
    for (int rf = 0; rf < 2; ++rf)
#pragma unroll
        for (int i = 0; i < 4; ++i) {
            int r = rowbase + rf * 16 + g * 4 + i;
            float v = acc[rf][i] + bv_;
            if (grp == 0) {
                size_t o = (size_t)(r >> 4) * 2048 + (c >> 5) * 512 +
                           ((c >> 3) & 3) * 128 + (r & 15) * 8 + (c & 7);
                qim[o] = (_Float16)v;
            } else if (grp == 1) {
                size_t o = (size_t)(r >> 5) * 4096 + ((r >> 4) & 1) * 2048 +
                           (c >> 5) * 512 + ((c >> 3) & 3) * 128 +
                           (r & 15) * 8 + (c & 7);
                kim[o] = (_Float16)v;
            } else {
                size_t o = (size_t)(r >> 5) * 4096 + (c >> 4) * 512 +
                           ((r >> 3) & 3) * 128 + (c & 15) * 8 + (r & 7);
                vim[o] = (_Float16)v;
            }
        }
}

// ---------------------------------------------------------------------------
// K2 v10 (R21-proven): swapped QK^T + half4 P-writes + fp16 partials.
// grid (MC=4, L/64, B); 4 waves, 16 q-rows each; KVBLK=64, 8 steps,
// 2-phase double buffer. LDS 72KB -> 2 blocks/CU.
// ---------------------------------------------------------------------------
__global__ __launch_bounds__(256, 2) void k2_attn(
        const _Float16* __restrict__ qim, const _Float16* __restrict__ kim,
        const _Float16* __restrict__ vim, _Float16* __restrict__ part) {
    int mc = blockIdx.x, qt = blockIdx.y, b = blockIdx.z;
    int t = threadIdx.x, lane = t & 63, wid = t >> 6;
    int cc = lane & 15, g = lane >> 4;

    __shared__ __attribute__((aligned(16))) _Float16 kb[2][8192];   // 16KB ea
    __shared__ __attribute__((aligned(16))) _Float16 vb[2][8192];   // 16KB ea
    __shared__ __attribute__((aligned(16))) _Float16 ps[4][1024];   // per-wave P

    int qrow = b * LL + qt * 64 + wid * 16;
    const _Float16* qb_ = qim + (size_t)(qrow >> 4) * 2048;
    half8_t qf[4];
#pragma unroll
    for (int s = 0; s < 4; ++s)
        qf[s] = *(const half8_t*)(qb_ + s * 512 + g * 128 + cc * 8);

    float4_t o[8];
#pragma unroll
    for (int cf = 0; cf < 8; ++cf) o[cf] = (float4_t){0.f, 0.f, 0.f, 0.f};

    int tbase = b * 64 + mc * 16;   // 32-row tile index base

    auto stageKV = [&](int mi, int buf) {
        const _Float16* ks = kim + (size_t)(tbase + mi * 2) * 4096;
        const _Float16* vs = vim + (size_t)(tbase + mi * 2) * 4096;
#pragma unroll
        for (int i = 0; i < 4; ++i) {
            gload16(ks + i * 2048 + t * 8, (char*)kb[buf] + i * 4096 + wid * 1024);
            gload16(vs + i * 2048 + t * 8, (char*)vb[buf] + i * 4096 + wid * 1024);
        }
    };

    stageKV(0, 0);
    __syncthreads();

#pragma unroll 1
    for (int mi = 0; mi < 8; ++mi) {
        int cb = mi & 1, nb = cb ^ 1;
        if (mi < 7) stageKV(mi + 1, nb);
        // ---- S^T = K Q^T (swapped): lane holds q=cc, m = cf*16 + g*4 + i
        float4_t sa[4];
#pragma unroll
        for (int cf = 0; cf < 4; ++cf) sa[cf] = (float4_t){0.f, 0.f, 0.f, 0.f};
#pragma unroll
        for (int cf = 0; cf < 4; ++cf)
#pragma unroll
            for (int s = 0; s < 4; ++s) {
                half8_t kf = *(const half8_t*)(kb[cb] + cf * 2048 + s * 512 +
                                               g * 128 + cc * 8);
                sa[cf] = MFMA16(kf, qf[s], sa[cf], 0, 0, 0);
            }
        // ---- P = cos(S) -> [m>>3][q][m&7]; i=0..3 contiguous -> one b64
#pragma unroll
        for (int cf = 0; cf < 4; ++cf) {
            half4_t h4;
#pragma unroll
            for (int i = 0; i < 4; ++i) {
                float rv = sa[cf][i] * INV2PI;
                rv = rv - floorf(rv);
                float cv;
                asm volatile("v_cos_f32 %0, %1" : "=v"(cv) : "v"(rv));
                h4[i] = (_Float16)cv;
            }
            int base = (cf * 2 + (g >> 1)) * 128 + cc * 8 + (g & 1) * 4;
            *(half4_t*)(&ps[wid][base]) = h4;
        }
        // ---- out += P @ V
#pragma unroll
        for (int ksv = 0; ksv < 2; ++ksv) {
            half8_t pa = *(const half8_t*)(&ps[wid][(ksv * 4 + g) * 128 + cc * 8]);
#pragma unroll
            for (int cf = 0; cf < 8; ++cf) {
                half8_t vbf = *(const half8_t*)(vb[cb] + ksv * 4096 + cf * 512 +
                                                g * 128 + cc * 8);
                o[cf] = MFMA16(pa, vbf, o[cf], 0, 0, 0);
            }
        }
        __syncthreads();
    }
    // ---- store fp16 partials: layout [MC][B][L][DK]
    _Float16* pp = part + ((size_t)(mc * BB + b) * LL + qt * 64 + wid * 16) * DK;
#pragma unroll
    for (int cf = 0; cf < 8; ++cf)
#pragma unroll
        for (int i = 0; i < 4; ++i)
            pp[(g * 4 + i) * DK + cf * 16 + cc] = (_Float16)o[cf][i];
}

// ---------------------------------------------------------------------------
// K3: out = sum of MC fp16 partials (fp32 accumulate, fp32 out)
// ---------------------------------------------------------------------------
__global__ __launch_bounds__(256) void k3_reduce(const _Float16* __restrict__ part,
                                                 float4_t* __restrict__ out) {
    constexpr int NT8 = MTOT * DK / 8;   // 131072 8-elem units per chunk
    int idx = blockIdx.x * 256 + threadIdx.x;
    const half8_t* p = (const half8_t*)part;
    float s[8];
#pragma unroll
    for (int e = 0; e < 8; ++e) s[e] = 0.f;
#pragma unroll
    for (int c = 0; c < MC; ++c) {
        half8_t v = p[idx + (size_t)c * NT8];
#pragma unroll
        for (int e = 0; e < 8; ++e) s[e] += (float)v[e];
    }
    float4_t o0 = {s[0], s[1], s[2], s[3]};
    float4_t o1 = {s[4], s[5], s[6], s[7]};
    out[idx * 2]     = o0;
    out[idx * 2 + 1] = o1;
}

// ---------------------------------------------------------------------------
extern "C" void kernel_launch(void* const* d_in, const int* in_sizes, int n_in,
                              void* d_out, int out_size, void* d_ws, size_t ws_size,
                              hipStream_t stream) {
    const float* x  = (const float*)d_in[0];
    const float* Wq = (const float*)d_in[1];
    const float* bq = (const float*)d_in[2];
    const float* Wk = (const float*)d_in[3];
    const float* bk = (const float*)d_in[4];
    const float* Wv = (const float*)d_in[5];
    const float* bv = (const float*)d_in[6];

    char* ws = (char*)d_ws;
    size_t off = 0;
    auto alloc = [&](size_t bytes) -> char* {
        char* p = ws + off;
        off += (bytes + 255) & ~(size_t)255;
        return p;
    };
    _Float16* wq6 = (_Float16*)alloc((size_t)DK * DM * 2);
    _Float16* wk6 = (_Float16*)alloc((size_t)DK * DM * 2);
    _Float16* wv6 = (_Float16*)alloc((size_t)DK * DM * 2);
    _Float16* qim = (_Float16*)alloc((size_t)MTOT * DK * 2);
    _Float16* kim = (_Float16*)alloc((size_t)MTOT * DK * 2);
    _Float16* vim = (_Float16*)alloc((size_t)MTOT * DK * 2);
    _Float16* part = (_Float16*)alloc((size_t)MC * MTOT * DK * 2);

    k0_wsplit<<<dim3(16, 3), 256, 0, stream>>>(Wq, Wk, Wv, wq6, wk6, wv6);
    k1_proj<<<dim3(MTOT / 32, 3), 512, 0, stream>>>(x, bq, bk, bv,
                                                    wq6, wk6, wv6, qim, kim, vim);
    k2_attn<<<dim3(MC, LL / 64, BB), 256, 0, stream>>>(qim, kim, vim, part);
    k3_reduce<<<(MTOT * DK / 8) / 256, 256, 0, stream>>>(part, (float4_t*)d_out);
}